// Round 22
// baseline (674.712 us; speedup 1.0000x reference)
//
#include <hip/hip_runtime.h>

// RLIF forward, persistent kernel, stamp-in-word sync.
// Round 22 = Round 21 (PASS @644us, champion) + TWO issue-timing code motions
// (instructions/protocol/datapath unchanged -> bit-identical output):
//  1. tx loads moved AFTER the poll/stage block: R21's loop-top order was
//     tx(HBM ~900cy) -> poll load -> s_waitcnt vmcnt(0), gating detect-verify
//     on the tx fetch every step. txv is only used in the epilogue (after the
//     MFMA chain) -- issue it post-detect and let MFMA hide it.
//  2. Optimistic 16B poll load issued at LOOP BOTTOM (after publish, before
//     out stores), loop-carried register, verified at next loop top. Being
//     older than the out-stores in the vmcnt FIFO it drains first; stale
//     samples fall into the unchanged guarded 8B retry + s_sleep(1).
// Publish (atomicExch rowpair u64, col-major, triple buffer), ys contents,
// A-frag bits, register 3-split Wr, mat-outer/ks-inner MFMA chain,
// z=acc_h0+red_h1, epilogue order: byte-identical to R21.

#define T_STEPS 256
#define BATCH   128
#define NNEUR   1024
#define DECAY_F 0.2f
#define THRESH  0.3f

typedef __attribute__((ext_vector_type(8))) short short8;
typedef __attribute__((ext_vector_type(4))) float f32x4;
typedef __attribute__((ext_vector_type(4))) unsigned uint4v;

union FU { short8 s; unsigned u[4]; };
union S8 { short8 s; unsigned short us[8]; };

__device__ __forceinline__ unsigned short f2bf_rn(float x) {
    unsigned u = __float_as_uint(x);
    return (unsigned short)((u + 0x7FFFu + ((u >> 16) & 1u)) >> 16);
}

__global__ void rlif_init(unsigned long long* __restrict__ qbuf) {
    int i = blockIdx.x * 256 + threadIdx.x;
    if (i < 3 * 8 * 512) qbuf[i] = 0xFFFFFFFF00000000ull;  // stamp never matches t
}

__global__ __launch_bounds__(256, 1)
void rlif_persist(const float* __restrict__ tx,   // [T][B][N]
                  const float* __restrict__ Wr,   // [N][N]
                  const float* __restrict__ br,   // [N]
                  float* __restrict__ out,        // [T][B][N]
                  unsigned long long* __restrict__ qbuf) // [3][8 grp][64 col][8 rowpair]
{
    extern __shared__ char smem[];
    float* red = (float*)smem;                                // [2 ct][16][16] f32
    unsigned short* ys = (unsigned short*)(smem + 2*16*16*4); // [16][66]

    const int tid = threadIdx.x;
    const int bb  = blockIdx.x >> 5;   // 0..7  batch-block (16 batches)
    const int ib  = blockIdx.x & 31;   // 0..31 neuron-block (32 neurons)
    const int i0  = ib * 32;
    const int b0  = bb * 16;
    const int w   = tid >> 6;          // wave 0..3
    const int l   = tid & 63;
    const int c   = l & 15;
    const int kg  = l >> 4;
    const int ct  = w & 1;             // neuron sub-tile (16 neurons)
    const int h   = w >> 1;            // k-half

    // ---- one-time: this lane's Wr B-fragments, exact 3-way bf16 split, in regs ----
    short8 fr0[16], fr1[16], fr2[16];
    {
        const float* wrow = Wr + (size_t)(i0 + ct * 16 + c) * NNEUR + h * 512 + kg * 8;
        #pragma unroll
        for (int ks = 0; ks < 16; ++ks) {
            float4 a = *(const float4*)(wrow + ks * 32);
            float4 b = *(const float4*)(wrow + ks * 32 + 4);
            float fv[8] = {a.x, a.y, a.z, a.w, b.x, b.y, b.z, b.w};
            S8 vh, vm, vl;
            #pragma unroll
            for (int e = 0; e < 8; ++e) {
                float fw = fv[e];
                unsigned short hb = f2bf_rn(fw);
                float hf = __uint_as_float((unsigned)hb << 16);
                float rm = fw - hf;                     // exact (Sterbenz)
                unsigned short mb = f2bf_rn(rm);
                float mf = __uint_as_float((unsigned)mb << 16);
                float rl = rm - mf;                     // exact; fits bf16
                vh.us[e] = hb; vm.us[e] = mb; vl.us[e] = f2bf_rn(rl);
            }
            fr0[ks] = vh.s; fr1[ks] = vm.s; fr2[ks] = vl.s;
        }
    }
    __syncthreads();

    const float brv = br[i0 + ct * 16 + c];
    float vreg[4] = {0.f, 0.f, 0.f, 0.f};
    const size_t BN = (size_t)BATCH * NNEUR;

    // poll geometry: thread owns qwords 2*tid, 2*tid+1 (col = tid>>2, pairs p0, p0+1)
    const int pcol = tid >> 2;          // producer column 0..63
    const int pp0  = (2 * tid) & 7;     // first rowpair (even) 0,2,4,6

    uint4v q;   // loop-carried optimistic sample [lo0, st0, lo1, st1]

    for (int t = 0; t < T_STEPS; ++t) {
        // ---- top: verify loop-carried sample, stage, guarded retry ----
        if (t > 0) {
            const unsigned long long* qb = qbuf + (size_t)((t - 1) % 3) * 4096 + bb * 512;
            const unsigned want = (unsigned)(t - 1);
            asm volatile("s_waitcnt vmcnt(0)" ::: "memory");
            __builtin_amdgcn_sched_barrier(0);
            unsigned pend = 0;
            if (q.y == want) {
                ys[(2 * pp0)     * 66 + pcol] = (unsigned short)(q.x & 0xFFFFu);
                ys[(2 * pp0 + 1) * 66 + pcol] = (unsigned short)(q.x >> 16);
            } else pend |= 1u;
            if (q.w == want) {
                ys[(2 * pp0 + 2) * 66 + pcol] = (unsigned short)(q.z & 0xFFFFu);
                ys[(2 * pp0 + 3) * 66 + pcol] = (unsigned short)(q.z >> 16);
            } else pend |= 2u;
            while (pend) {
                #pragma unroll
                for (int k = 0; k < 2; ++k) {
                    if (pend & (1u << k)) {
                        unsigned long long qv = __hip_atomic_load(qb + 2 * tid + k,
                                                                  __ATOMIC_RELAXED, __HIP_MEMORY_SCOPE_AGENT);
                        if ((unsigned)(qv >> 32) == want) {
                            int p = pp0 + k;
                            ys[(2 * p)     * 66 + pcol] = (unsigned short)(qv & 0xFFFFu);
                            ys[(2 * p + 1) * 66 + pcol] = (unsigned short)((qv >> 16) & 0xFFFFu);
                            pend &= ~(1u << k);
                        }
                    }
                }
                if (pend) __builtin_amdgcn_s_sleep(1);
            }
        }

        // tx prefetch AFTER detect (was before: gated detect on HBM latency);
        // hides under barrier-1 + unpack + MFMA, consumed only in the epilogue.
        float txv[4];
        if (h == 0) {
            #pragma unroll
            for (int j = 0; j < 4; ++j)
                txv[j] = tx[(size_t)t * BN + (size_t)(b0 + kg * 4 + j) * NNEUR + i0 + ct * 16 + c];
        }
        __syncthreads();

        f32x4 acc = {0.f, 0.f, 0.f, 0.f};
        if (t > 0) {
            // A-frags: bf16 1.0 / 0.0 bit patterns (identical to rounds 2/5/6/14/16/20/21)
            short8 afr[16];
            #pragma unroll
            for (int ks = 0; ks < 16; ++ks) {
                unsigned wv = *(const unsigned*)(ys + c * 66 + 2 * (h * 16 + ks));
                unsigned byt = (wv >> (kg * 8)) & 0xFFu;
                FU f;
                #pragma unroll
                for (int q2 = 0; q2 < 4; ++q2) {
                    f.u[q2] = (((byt >> (2 * q2)) & 1u) ? 0x00003F80u : 0u)
                            | (((byt >> (2 * q2 + 1)) & 1u) ? 0x3F800000u : 0u);
                }
                afr[ks] = f.s;
            }
            // single accumulator chain, mat-outer / ks-inner — proven exact order
            #pragma unroll
            for (int ks = 0; ks < 16; ++ks)
                acc = __builtin_amdgcn_mfma_f32_16x16x32_bf16(afr[ks], fr0[ks], acc, 0, 0, 0);
            #pragma unroll
            for (int ks = 0; ks < 16; ++ks)
                acc = __builtin_amdgcn_mfma_f32_16x16x32_bf16(afr[ks], fr1[ks], acc, 0, 0, 0);
            #pragma unroll
            for (int ks = 0; ks < 16; ++ks)
                acc = __builtin_amdgcn_mfma_f32_16x16x32_bf16(afr[ks], fr2[ks], acc, 0, 0, 0);
        }

        if (h == 1) {
            #pragma unroll
            for (int j = 0; j < 4; ++j)
                red[ct * 256 + (kg * 4 + j) * 16 + c] = acc[j];
        }
        __syncthreads();

        int sp4[4];
        if (h == 0) {
            unsigned long long* pq = qbuf + (size_t)(t % 3) * 4096 + bb * 512;
            unsigned long long mball[4];
            #pragma unroll
            for (int j = 0; j < 4; ++j) {
                float z  = acc[j] + red[ct * 256 + (kg * 4 + j) * 16 + c];
                float x  = (txv[j] + z) + brv;
                float vv = DECAY_F * vreg[j] + x;
                int   sp = vv > THRESH;
                vreg[j]  = sp ? 0.f : vv;
                sp4[j]   = sp;
                mball[j] = __ballot(sp != 0);
            }
            // publish FIRST: rowpair qwords, col-major layout (flat = col*8 + p)
            if (c == 0 || c == 2) {
                int a = c >> 1;
                unsigned lo = (unsigned)((mball[2 * a]     >> (kg * 16)) & 0xFFFFu);
                unsigned hi = (unsigned)((mball[2 * a + 1] >> (kg * 16)) & 0xFFFFu);
                unsigned long long qv = ((unsigned long long)(unsigned)t << 32)
                                      | ((unsigned long long)hi << 16) | lo;
                atomicExch(&pq[(ib * 2 + ct) * 8 + (kg * 2 + a)], qv);
            }
        }

        // ---- bottom: issue optimistic 16B sample for step t+1 (all threads) ----
        {
            const unsigned long long* qn = qbuf + (size_t)(t % 3) * 4096 + bb * 512;
            asm volatile("global_load_dwordx4 %0, %1, off sc0 sc1"
                         : "=&v"(q) : "v"(qn + 2 * tid) : "memory");
        }

        if (h == 0) {
            float* op = out + (size_t)t * BN;
            #pragma unroll
            for (int j = 0; j < 4; ++j)
                op[(size_t)(b0 + kg * 4 + j) * NNEUR + i0 + ct * 16 + c] = sp4[j] ? 1.f : 0.f;
        }
        // no end-of-step barrier: stamp polling is the synchronization
    }
}

extern "C" void kernel_launch(void* const* d_in, const int* in_sizes, int n_in,
                              void* d_out, int out_size, void* d_ws, size_t ws_size,
                              hipStream_t stream)
{
    const float* tx = (const float*)d_in[0];
    const float* Wr = (const float*)d_in[1];
    const float* br = (const float*)d_in[2];
    float* out = (float*)d_out;
    unsigned long long* qbuf = (unsigned long long*)d_ws;   // [3][8][512] u64 = 96 KB

    const int lds_bytes = 2 * 16 * 16 * 4 + 16 * 66 * 2;   // 4160
    hipFuncSetAttribute(reinterpret_cast<const void*>(rlif_persist),
                        hipFuncAttributeMaxDynamicSharedMemorySize, lds_bytes);

    rlif_init<<<dim3(48), dim3(256), 0, stream>>>(qbuf);
    rlif_persist<<<dim3(256), dim3(256), lds_bytes, stream>>>(tx, Wr, br, out, qbuf);
}

// Round 23
// 658.950 us; speedup vs baseline: 1.0239x; 1.0239x over previous
//
#include <hip/hip_runtime.h>

// RLIF forward, persistent kernel, stamp-in-word sync.
// Round 23 = Round 21 (PASS @644us, champion) + ONE code motion (the safe half
// of R22's bundle): tx loads move from BEFORE the poll block to AFTER the
// poll/stage block. R21's detect did vmcnt(0) with 4 cold tx HBM loads
// (~900cy) in the FIFO -> verify gated on HBM instead of poll RTT. txv is
// consumed only in the epilogue (~1.5us later) so it hides under
// barrier+unpack+MFMA. R22 bundled this with an early poll-issue (loop
// bottom) which cost more than this gained (675); the poll load here stays at
// R21's exact loop-top issue point.
// Everything else (publish atomicExch rowpair u64 col-major, triple buffer,
// 16B optimistic poll + guarded 8B retry + s_sleep(1), ys contents, A-frag
// bits, register 3-split Wr, mat-outer/ks-inner MFMA chain, z=acc_h0+red_h1,
// epilogue order): byte-identical to R21 -> bit-identical output.

#define T_STEPS 256
#define BATCH   128
#define NNEUR   1024
#define DECAY_F 0.2f
#define THRESH  0.3f

typedef __attribute__((ext_vector_type(8))) short short8;
typedef __attribute__((ext_vector_type(4))) float f32x4;
typedef __attribute__((ext_vector_type(4))) unsigned uint4v;

union FU { short8 s; unsigned u[4]; };
union S8 { short8 s; unsigned short us[8]; };

__device__ __forceinline__ unsigned short f2bf_rn(float x) {
    unsigned u = __float_as_uint(x);
    return (unsigned short)((u + 0x7FFFu + ((u >> 16) & 1u)) >> 16);
}

__global__ void rlif_init(unsigned long long* __restrict__ qbuf) {
    int i = blockIdx.x * 256 + threadIdx.x;
    if (i < 3 * 8 * 512) qbuf[i] = 0xFFFFFFFF00000000ull;  // stamp never matches t
}

__global__ __launch_bounds__(256, 1)
void rlif_persist(const float* __restrict__ tx,   // [T][B][N]
                  const float* __restrict__ Wr,   // [N][N]
                  const float* __restrict__ br,   // [N]
                  float* __restrict__ out,        // [T][B][N]
                  unsigned long long* __restrict__ qbuf) // [3][8 grp][64 col][8 rowpair]
{
    extern __shared__ char smem[];
    float* red = (float*)smem;                                // [2 ct][16][16] f32
    unsigned short* ys = (unsigned short*)(smem + 2*16*16*4); // [16][66]

    const int tid = threadIdx.x;
    const int bb  = blockIdx.x >> 5;   // 0..7  batch-block (16 batches)
    const int ib  = blockIdx.x & 31;   // 0..31 neuron-block (32 neurons)
    const int i0  = ib * 32;
    const int b0  = bb * 16;
    const int w   = tid >> 6;          // wave 0..3
    const int l   = tid & 63;
    const int c   = l & 15;
    const int kg  = l >> 4;
    const int ct  = w & 1;             // neuron sub-tile (16 neurons)
    const int h   = w >> 1;            // k-half

    // ---- one-time: this lane's Wr B-fragments, exact 3-way bf16 split, in regs ----
    short8 fr0[16], fr1[16], fr2[16];
    {
        const float* wrow = Wr + (size_t)(i0 + ct * 16 + c) * NNEUR + h * 512 + kg * 8;
        #pragma unroll
        for (int ks = 0; ks < 16; ++ks) {
            float4 a = *(const float4*)(wrow + ks * 32);
            float4 b = *(const float4*)(wrow + ks * 32 + 4);
            float fv[8] = {a.x, a.y, a.z, a.w, b.x, b.y, b.z, b.w};
            S8 vh, vm, vl;
            #pragma unroll
            for (int e = 0; e < 8; ++e) {
                float fw = fv[e];
                unsigned short hb = f2bf_rn(fw);
                float hf = __uint_as_float((unsigned)hb << 16);
                float rm = fw - hf;                     // exact (Sterbenz)
                unsigned short mb = f2bf_rn(rm);
                float mf = __uint_as_float((unsigned)mb << 16);
                float rl = rm - mf;                     // exact; fits bf16
                vh.us[e] = hb; vm.us[e] = mb; vl.us[e] = f2bf_rn(rl);
            }
            fr0[ks] = vh.s; fr1[ks] = vm.s; fr2[ks] = vl.s;
        }
    }
    __syncthreads();

    const float brv = br[i0 + ct * 16 + c];
    float vreg[4] = {0.f, 0.f, 0.f, 0.f};
    const size_t BN = (size_t)BATCH * NNEUR;

    // poll geometry: thread owns qwords 2*tid, 2*tid+1 (col = tid>>2, pairs p0, p0+1)
    const int pcol = tid >> 2;          // producer column 0..63
    const int pp0  = (2 * tid) & 7;     // first rowpair (even) 0,2,4,6

    for (int t = 0; t < T_STEPS; ++t) {
        // ---- stage spikes of step t-1: paired-qword 16B poll + guarded 8B retry ----
        if (t > 0) {
            const unsigned long long* qb = qbuf + (size_t)((t - 1) % 3) * 4096 + bb * 512;
            const unsigned want = (unsigned)(t - 1);
            uint4v q;   // [lo0, st0, lo1, st1]
            asm volatile("global_load_dwordx4 %0, %1, off sc0 sc1"
                         : "=&v"(q) : "v"(qb + 2 * tid) : "memory");
            asm volatile("s_waitcnt vmcnt(0)" ::: "memory");
            __builtin_amdgcn_sched_barrier(0);
            unsigned pend = 0;
            if (q.y == want) {
                ys[(2 * pp0)     * 66 + pcol] = (unsigned short)(q.x & 0xFFFFu);
                ys[(2 * pp0 + 1) * 66 + pcol] = (unsigned short)(q.x >> 16);
            } else pend |= 1u;
            if (q.w == want) {
                ys[(2 * pp0 + 2) * 66 + pcol] = (unsigned short)(q.z & 0xFFFFu);
                ys[(2 * pp0 + 3) * 66 + pcol] = (unsigned short)(q.z >> 16);
            } else pend |= 2u;
            while (pend) {
                #pragma unroll
                for (int k = 0; k < 2; ++k) {
                    if (pend & (1u << k)) {
                        unsigned long long qv = __hip_atomic_load(qb + 2 * tid + k,
                                                                  __ATOMIC_RELAXED, __HIP_MEMORY_SCOPE_AGENT);
                        if ((unsigned)(qv >> 32) == want) {
                            int p = pp0 + k;
                            ys[(2 * p)     * 66 + pcol] = (unsigned short)(qv & 0xFFFFu);
                            ys[(2 * p + 1) * 66 + pcol] = (unsigned short)((qv >> 16) & 0xFFFFu);
                            pend &= ~(1u << k);
                        }
                    }
                }
                if (pend) __builtin_amdgcn_s_sleep(1);
            }
        }

        // tx loads AFTER detect (the one change vs R21): consumed only in the
        // epilogue; latency hides under barrier-1 + unpack + MFMA chain.
        float txv[4];
        if (h == 0) {
            #pragma unroll
            for (int j = 0; j < 4; ++j)
                txv[j] = tx[(size_t)t * BN + (size_t)(b0 + kg * 4 + j) * NNEUR + i0 + ct * 16 + c];
        }
        __syncthreads();

        f32x4 acc = {0.f, 0.f, 0.f, 0.f};
        if (t > 0) {
            // A-frags: bf16 1.0 / 0.0 bit patterns (identical to rounds 2/5/6/14/16/20/21)
            short8 afr[16];
            #pragma unroll
            for (int ks = 0; ks < 16; ++ks) {
                unsigned wv = *(const unsigned*)(ys + c * 66 + 2 * (h * 16 + ks));
                unsigned byt = (wv >> (kg * 8)) & 0xFFu;
                FU f;
                #pragma unroll
                for (int q2 = 0; q2 < 4; ++q2) {
                    f.u[q2] = (((byt >> (2 * q2)) & 1u) ? 0x00003F80u : 0u)
                            | (((byt >> (2 * q2 + 1)) & 1u) ? 0x3F800000u : 0u);
                }
                afr[ks] = f.s;
            }
            // single accumulator chain, mat-outer / ks-inner — proven exact order
            #pragma unroll
            for (int ks = 0; ks < 16; ++ks)
                acc = __builtin_amdgcn_mfma_f32_16x16x32_bf16(afr[ks], fr0[ks], acc, 0, 0, 0);
            #pragma unroll
            for (int ks = 0; ks < 16; ++ks)
                acc = __builtin_amdgcn_mfma_f32_16x16x32_bf16(afr[ks], fr1[ks], acc, 0, 0, 0);
            #pragma unroll
            for (int ks = 0; ks < 16; ++ks)
                acc = __builtin_amdgcn_mfma_f32_16x16x32_bf16(afr[ks], fr2[ks], acc, 0, 0, 0);
        }

        if (h == 1) {
            #pragma unroll
            for (int j = 0; j < 4; ++j)
                red[ct * 256 + (kg * 4 + j) * 16 + c] = acc[j];
        }
        __syncthreads();

        if (h == 0) {
            float* op = out + (size_t)t * BN;
            unsigned long long* pq = qbuf + (size_t)(t % 3) * 4096 + bb * 512;
            int sp4[4];
            unsigned long long mball[4];
            #pragma unroll
            for (int j = 0; j < 4; ++j) {
                float z  = acc[j] + red[ct * 256 + (kg * 4 + j) * 16 + c];
                float x  = (txv[j] + z) + brv;
                float vv = DECAY_F * vreg[j] + x;
                int   sp = vv > THRESH;
                vreg[j]  = sp ? 0.f : vv;
                sp4[j]   = sp;
                mball[j] = __ballot(sp != 0);
            }
            // publish FIRST: rowpair qwords, col-major layout (flat = col*8 + p)
            if (c == 0 || c == 2) {
                int a = c >> 1;
                unsigned lo = (unsigned)((mball[2 * a]     >> (kg * 16)) & 0xFFFFu);
                unsigned hi = (unsigned)((mball[2 * a + 1] >> (kg * 16)) & 0xFFFFu);
                unsigned long long qv = ((unsigned long long)(unsigned)t << 32)
                                      | ((unsigned long long)hi << 16) | lo;
                atomicExch(&pq[(ib * 2 + ct) * 8 + (kg * 2 + a)], qv);
            }
            // then the out-slab stores (no intra-kernel consumer)
            #pragma unroll
            for (int j = 0; j < 4; ++j)
                op[(size_t)(b0 + kg * 4 + j) * NNEUR + i0 + ct * 16 + c] = sp4[j] ? 1.f : 0.f;
        }
        // no end-of-step barrier: stamp polling is the synchronization
    }
}

extern "C" void kernel_launch(void* const* d_in, const int* in_sizes, int n_in,
                              void* d_out, int out_size, void* d_ws, size_t ws_size,
                              hipStream_t stream)
{
    const float* tx = (const float*)d_in[0];
    const float* Wr = (const float*)d_in[1];
    const float* br = (const float*)d_in[2];
    float* out = (float*)d_out;
    unsigned long long* qbuf = (unsigned long long*)d_ws;   // [3][8][512] u64 = 96 KB

    const int lds_bytes = 2 * 16 * 16 * 4 + 16 * 66 * 2;   // 4160
    hipFuncSetAttribute(reinterpret_cast<const void*>(rlif_persist),
                        hipFuncAttributeMaxDynamicSharedMemorySize, lds_bytes);

    rlif_init<<<dim3(48), dim3(256), 0, stream>>>(qbuf);
    rlif_persist<<<dim3(256), dim3(256), lds_bytes, stream>>>(tx, Wr, br, out, qbuf);
}

// Round 24
// 643.997 us; speedup vs baseline: 1.0477x; 1.0232x over previous
//
#include <hip/hip_runtime.h>

// RLIF forward, persistent kernel, stamp-in-word sync. CHAMPION (R21, 644us).
// Round 24 = Round 21 byte-for-byte restore after R22/R23 refinements both
// regressed (675/659): the R21 local optimum is confirmed converged.
// Structure: 8 groups x 32 wgs (wg = 16 batches x 32 neurons); register-
// resident 3-way bf16 Wr split (exact h+m+l); rowpair u64 publish
// (t<<32 | row(2a+1)<<16 | row(2a)) via atomicExch, col-major layout, triple
// buffer; consume via ONE global_load_dwordx4 sc0 sc1 (two self-stamped
// qwords, 1 fabric RTT) + guarded 8B atomic retry + s_sleep(1).
// Datapath bit-exact: A-frags from ballot bits (bf16 1.0/0.0), single
// accumulator chain mat-outer/ks-inner, z = acc_h0 + red_h1, epilogue order
// (tx + z) + br -> decay -> threshold -> hard reset.

#define T_STEPS 256
#define BATCH   128
#define NNEUR   1024
#define DECAY_F 0.2f
#define THRESH  0.3f

typedef __attribute__((ext_vector_type(8))) short short8;
typedef __attribute__((ext_vector_type(4))) float f32x4;
typedef __attribute__((ext_vector_type(4))) unsigned uint4v;

union FU { short8 s; unsigned u[4]; };
union S8 { short8 s; unsigned short us[8]; };

__device__ __forceinline__ unsigned short f2bf_rn(float x) {
    unsigned u = __float_as_uint(x);
    return (unsigned short)((u + 0x7FFFu + ((u >> 16) & 1u)) >> 16);
}

__global__ void rlif_init(unsigned long long* __restrict__ qbuf) {
    int i = blockIdx.x * 256 + threadIdx.x;
    if (i < 3 * 8 * 512) qbuf[i] = 0xFFFFFFFF00000000ull;  // stamp never matches t
}

__global__ __launch_bounds__(256, 1)
void rlif_persist(const float* __restrict__ tx,   // [T][B][N]
                  const float* __restrict__ Wr,   // [N][N]
                  const float* __restrict__ br,   // [N]
                  float* __restrict__ out,        // [T][B][N]
                  unsigned long long* __restrict__ qbuf) // [3][8 grp][64 col][8 rowpair]
{
    extern __shared__ char smem[];
    float* red = (float*)smem;                                // [2 ct][16][16] f32
    unsigned short* ys = (unsigned short*)(smem + 2*16*16*4); // [16][66]

    const int tid = threadIdx.x;
    const int bb  = blockIdx.x >> 5;   // 0..7  batch-block (16 batches)
    const int ib  = blockIdx.x & 31;   // 0..31 neuron-block (32 neurons)
    const int i0  = ib * 32;
    const int b0  = bb * 16;
    const int w   = tid >> 6;          // wave 0..3
    const int l   = tid & 63;
    const int c   = l & 15;
    const int kg  = l >> 4;
    const int ct  = w & 1;             // neuron sub-tile (16 neurons)
    const int h   = w >> 1;            // k-half

    // ---- one-time: this lane's Wr B-fragments, exact 3-way bf16 split, in regs ----
    short8 fr0[16], fr1[16], fr2[16];
    {
        const float* wrow = Wr + (size_t)(i0 + ct * 16 + c) * NNEUR + h * 512 + kg * 8;
        #pragma unroll
        for (int ks = 0; ks < 16; ++ks) {
            float4 a = *(const float4*)(wrow + ks * 32);
            float4 b = *(const float4*)(wrow + ks * 32 + 4);
            float fv[8] = {a.x, a.y, a.z, a.w, b.x, b.y, b.z, b.w};
            S8 vh, vm, vl;
            #pragma unroll
            for (int e = 0; e < 8; ++e) {
                float fw = fv[e];
                unsigned short hb = f2bf_rn(fw);
                float hf = __uint_as_float((unsigned)hb << 16);
                float rm = fw - hf;                     // exact (Sterbenz)
                unsigned short mb = f2bf_rn(rm);
                float mf = __uint_as_float((unsigned)mb << 16);
                float rl = rm - mf;                     // exact; fits bf16
                vh.us[e] = hb; vm.us[e] = mb; vl.us[e] = f2bf_rn(rl);
            }
            fr0[ks] = vh.s; fr1[ks] = vm.s; fr2[ks] = vl.s;
        }
    }
    __syncthreads();

    const float brv = br[i0 + ct * 16 + c];
    float vreg[4] = {0.f, 0.f, 0.f, 0.f};
    const size_t BN = (size_t)BATCH * NNEUR;

    // poll geometry: thread owns qwords 2*tid, 2*tid+1 (col = tid>>2, pairs p0, p0+1)
    const int pcol = tid >> 2;          // producer column 0..63
    const int pp0  = (2 * tid) & 7;     // first rowpair (even) 0,2,4,6

    for (int t = 0; t < T_STEPS; ++t) {
        float txv[4];
        if (h == 0) {
            #pragma unroll
            for (int j = 0; j < 4; ++j)
                txv[j] = tx[(size_t)t * BN + (size_t)(b0 + kg * 4 + j) * NNEUR + i0 + ct * 16 + c];
        }

        // ---- stage spikes of step t-1: paired-qword 16B poll + guarded 8B retry ----
        if (t > 0) {
            const unsigned long long* qb = qbuf + (size_t)((t - 1) % 3) * 4096 + bb * 512;
            const unsigned want = (unsigned)(t - 1);
            uint4v q;   // [lo0, st0, lo1, st1]
            asm volatile("global_load_dwordx4 %0, %1, off sc0 sc1"
                         : "=&v"(q) : "v"(qb + 2 * tid) : "memory");
            asm volatile("s_waitcnt vmcnt(0)" ::: "memory");
            __builtin_amdgcn_sched_barrier(0);
            unsigned pend = 0;
            if (q.y == want) {
                ys[(2 * pp0)     * 66 + pcol] = (unsigned short)(q.x & 0xFFFFu);
                ys[(2 * pp0 + 1) * 66 + pcol] = (unsigned short)(q.x >> 16);
            } else pend |= 1u;
            if (q.w == want) {
                ys[(2 * pp0 + 2) * 66 + pcol] = (unsigned short)(q.z & 0xFFFFu);
                ys[(2 * pp0 + 3) * 66 + pcol] = (unsigned short)(q.z >> 16);
            } else pend |= 2u;
            while (pend) {
                #pragma unroll
                for (int k = 0; k < 2; ++k) {
                    if (pend & (1u << k)) {
                        unsigned long long qv = __hip_atomic_load(qb + 2 * tid + k,
                                                                  __ATOMIC_RELAXED, __HIP_MEMORY_SCOPE_AGENT);
                        if ((unsigned)(qv >> 32) == want) {
                            int p = pp0 + k;
                            ys[(2 * p)     * 66 + pcol] = (unsigned short)(qv & 0xFFFFu);
                            ys[(2 * p + 1) * 66 + pcol] = (unsigned short)((qv >> 16) & 0xFFFFu);
                            pend &= ~(1u << k);
                        }
                    }
                }
                if (pend) __builtin_amdgcn_s_sleep(1);
            }
        }
        __syncthreads();

        f32x4 acc = {0.f, 0.f, 0.f, 0.f};
        if (t > 0) {
            // A-frags: bf16 1.0 / 0.0 bit patterns (identical to rounds 2/5/6/14/16/20)
            short8 afr[16];
            #pragma unroll
            for (int ks = 0; ks < 16; ++ks) {
                unsigned wv = *(const unsigned*)(ys + c * 66 + 2 * (h * 16 + ks));
                unsigned byt = (wv >> (kg * 8)) & 0xFFu;
                FU f;
                #pragma unroll
                for (int q2 = 0; q2 < 4; ++q2) {
                    f.u[q2] = (((byt >> (2 * q2)) & 1u) ? 0x00003F80u : 0u)
                            | (((byt >> (2 * q2 + 1)) & 1u) ? 0x3F800000u : 0u);
                }
                afr[ks] = f.s;
            }
            // single accumulator chain, mat-outer / ks-inner — proven exact order
            #pragma unroll
            for (int ks = 0; ks < 16; ++ks)
                acc = __builtin_amdgcn_mfma_f32_16x16x32_bf16(afr[ks], fr0[ks], acc, 0, 0, 0);
            #pragma unroll
            for (int ks = 0; ks < 16; ++ks)
                acc = __builtin_amdgcn_mfma_f32_16x16x32_bf16(afr[ks], fr1[ks], acc, 0, 0, 0);
            #pragma unroll
            for (int ks = 0; ks < 16; ++ks)
                acc = __builtin_amdgcn_mfma_f32_16x16x32_bf16(afr[ks], fr2[ks], acc, 0, 0, 0);
        }

        if (h == 1) {
            #pragma unroll
            for (int j = 0; j < 4; ++j)
                red[ct * 256 + (kg * 4 + j) * 16 + c] = acc[j];
        }
        __syncthreads();

        if (h == 0) {
            float* op = out + (size_t)t * BN;
            unsigned long long* pq = qbuf + (size_t)(t % 3) * 4096 + bb * 512;
            int sp4[4];
            unsigned long long mball[4];
            #pragma unroll
            for (int j = 0; j < 4; ++j) {
                float z  = acc[j] + red[ct * 256 + (kg * 4 + j) * 16 + c];
                float x  = (txv[j] + z) + brv;
                float vv = DECAY_F * vreg[j] + x;
                int   sp = vv > THRESH;
                vreg[j]  = sp ? 0.f : vv;
                sp4[j]   = sp;
                mball[j] = __ballot(sp != 0);
            }
            // publish FIRST: rowpair qwords, col-major layout (flat = col*8 + p)
            if (c == 0 || c == 2) {
                int a = c >> 1;
                unsigned lo = (unsigned)((mball[2 * a]     >> (kg * 16)) & 0xFFFFu);
                unsigned hi = (unsigned)((mball[2 * a + 1] >> (kg * 16)) & 0xFFFFu);
                unsigned long long qv = ((unsigned long long)(unsigned)t << 32)
                                      | ((unsigned long long)hi << 16) | lo;
                atomicExch(&pq[(ib * 2 + ct) * 8 + (kg * 2 + a)], qv);
            }
            // then the out-slab stores (no intra-kernel consumer)
            #pragma unroll
            for (int j = 0; j < 4; ++j)
                op[(size_t)(b0 + kg * 4 + j) * NNEUR + i0 + ct * 16 + c] = sp4[j] ? 1.f : 0.f;
        }
        // no end-of-step barrier: stamp polling is the synchronization
    }
}

extern "C" void kernel_launch(void* const* d_in, const int* in_sizes, int n_in,
                              void* d_out, int out_size, void* d_ws, size_t ws_size,
                              hipStream_t stream)
{
    const float* tx = (const float*)d_in[0];
    const float* Wr = (const float*)d_in[1];
    const float* br = (const float*)d_in[2];
    float* out = (float*)d_out;
    unsigned long long* qbuf = (unsigned long long*)d_ws;   // [3][8][512] u64 = 96 KB

    const int lds_bytes = 2 * 16 * 16 * 4 + 16 * 66 * 2;   // 4160
    hipFuncSetAttribute(reinterpret_cast<const void*>(rlif_persist),
                        hipFuncAttributeMaxDynamicSharedMemorySize, lds_bytes);

    rlif_init<<<dim3(48), dim3(256), 0, stream>>>(qbuf);
    rlif_persist<<<dim3(256), dim3(256), lds_bytes, stream>>>(tx, Wr, br, out, qbuf);
}